// Round 2
// baseline (137.813 us; speedup 1.0000x reference)
//
#include <hip/hip_runtime.h>
#include <hip/hip_bf16.h>

#define N 8192
#define FIN 128
#define FOUT 64
#define CSPLIT 4

typedef __attribute__((ext_vector_type(4))) float f32x4;
typedef __attribute__((ext_vector_type(4))) int i32x4;
typedef __attribute__((ext_vector_type(8))) short bf16x8;

__device__ __forceinline__ short f2bf(float x) {
    __hip_bfloat16 b = __float2bfloat16(x);
    union { __hip_bfloat16 b; short s; } u; u.b = b; return u.s;
}

// Kernel 1: Wh = h @ W (store transposed bf16), s_src = Wh@a1, s_dst = Wh@a2 (fp32)
__global__ __launch_bounds__(256) void wh_kernel(
    const float* __restrict__ h, const float* __restrict__ W,
    const float* __restrict__ a,
    __hip_bfloat16* __restrict__ whT, float* __restrict__ s_src,
    float* __restrict__ s_dst) {
    const int wave = threadIdx.x >> 6;
    const int lane = threadIdx.x & 63;   // lane = output feature f
    const int row = blockIdx.x * 4 + wave;
    const float* hr = h + (size_t)row * FIN;
    float acc = 0.f;
#pragma unroll 8
    for (int k = 0; k < FIN; ++k) {
        acc += hr[k] * W[k * FOUT + lane];
    }
    whT[(size_t)lane * N + row] = __float2bfloat16(acc);
    float s1 = acc * a[lane];
    float s2 = acc * a[FOUT + lane];
#pragma unroll
    for (int m = 32; m >= 1; m >>= 1) {
        s1 += __shfl_xor(s1, m, 64);
        s2 += __shfl_xor(s2, m, 64);
    }
    if (lane == 0) { s_src[row] = s1; s_dst[row] = s2; }
}

// Kernel 2: partial masked-softmax attention numerators via MFMA.
// Grid = (N/16) * CSPLIT blocks. Block b: row-group rg = b >> 2, chunk c = b & 3.
// Block owns 16 rows x 2048 cols; wave w owns 512 cols of that.
__global__ __launch_bounds__(256) void gat_partial(
    const int* __restrict__ adj, const __hip_bfloat16* __restrict__ whT,
    const float* __restrict__ s_src, const float* __restrict__ s_dst,
    float* __restrict__ numP, float* __restrict__ denP) {
    const int tid = threadIdx.x;
    const int w = tid >> 6, lane = tid & 63;
    const int m = lane & 15, kg = lane >> 4;
    const int rg = blockIdx.x >> 2;
    const int c = blockIdx.x & 3;
    const int ibase = rg * 16;
    const int row = ibase + m;
    const float ssrc = s_src[row];
    const int jbase = c * (N / CSPLIT) + w * (N / CSPLIT / 4);  // 512-wide wave chunk

    const int* ap = adj + (size_t)row * N + jbase;
    const float* dp = s_dst + jbase;
    const __hip_bfloat16* wp = whT + (size_t)m * N + jbase;

    f32x4 acc0 = {0,0,0,0}, acc1 = {0,0,0,0}, acc2 = {0,0,0,0}, acc3 = {0,0,0,0};
    float dsum = 0.f;

    const int STEPS = (N / CSPLIT / 4) / 32;  // 16
    int jl = kg * 8;

    i32x4 a0 = *(const i32x4*)(ap + jl);
    i32x4 a1 = *(const i32x4*)(ap + jl + 4);
    f32x4 d0 = *(const f32x4*)(dp + jl);
    f32x4 d1 = *(const f32x4*)(dp + jl + 4);
    bf16x8 b0 = *(const bf16x8*)(wp + (size_t)0 * 16 * N + jl);
    bf16x8 b1 = *(const bf16x8*)(wp + (size_t)1 * 16 * N + jl);
    bf16x8 b2 = *(const bf16x8*)(wp + (size_t)2 * 16 * N + jl);
    bf16x8 b3 = *(const bf16x8*)(wp + (size_t)3 * 16 * N + jl);

    for (int s = 0; s < STEPS; ++s) {
        const int jln = (s + 1 < STEPS) ? (jl + 32) : jl;
        i32x4 na0 = *(const i32x4*)(ap + jln);
        i32x4 na1 = *(const i32x4*)(ap + jln + 4);
        f32x4 nd0 = *(const f32x4*)(dp + jln);
        f32x4 nd1 = *(const f32x4*)(dp + jln + 4);
        bf16x8 nb0 = *(const bf16x8*)(wp + (size_t)0 * 16 * N + jln);
        bf16x8 nb1 = *(const bf16x8*)(wp + (size_t)1 * 16 * N + jln);
        bf16x8 nb2 = *(const bf16x8*)(wp + (size_t)2 * 16 * N + jln);
        bf16x8 nb3 = *(const bf16x8*)(wp + (size_t)3 * 16 * N + jln);

        bf16x8 afr;
#pragma unroll
        for (int e = 0; e < 4; ++e) {
            float x = ssrc + d0[e];
            x = (x >= 0.f) ? x : 0.2f * x;
            float p = (a0[e] > 0) ? __expf(x) : 0.f;
            dsum += p;
            afr[e] = f2bf(p);
        }
#pragma unroll
        for (int e = 0; e < 4; ++e) {
            float x = ssrc + d1[e];
            x = (x >= 0.f) ? x : 0.2f * x;
            float p = (a1[e] > 0) ? __expf(x) : 0.f;
            dsum += p;
            afr[4 + e] = f2bf(p);
        }

        acc0 = __builtin_amdgcn_mfma_f32_16x16x32_bf16(afr, b0, acc0, 0, 0, 0);
        acc1 = __builtin_amdgcn_mfma_f32_16x16x32_bf16(afr, b1, acc1, 0, 0, 0);
        acc2 = __builtin_amdgcn_mfma_f32_16x16x32_bf16(afr, b2, acc2, 0, 0, 0);
        acc3 = __builtin_amdgcn_mfma_f32_16x16x32_bf16(afr, b3, acc3, 0, 0, 0);

        a0 = na0; a1 = na1; d0 = nd0; d1 = nd1;
        b0 = nb0; b1 = nb1; b2 = nb2; b3 = nb3;
        jl = jln;
    }

    dsum += __shfl_xor(dsum, 16, 64);
    dsum += __shfl_xor(dsum, 32, 64);

    __shared__ float pC[4][16][FOUT];
    __shared__ float pD[4][16];
#pragma unroll
    for (int r = 0; r < 4; ++r) {
        pC[w][kg * 4 + r][0 * 16 + m] = acc0[r];
        pC[w][kg * 4 + r][1 * 16 + m] = acc1[r];
        pC[w][kg * 4 + r][2 * 16 + m] = acc2[r];
        pC[w][kg * 4 + r][3 * 16 + m] = acc3[r];
    }
    if (kg == 0) pD[w][m] = dsum;
    __syncthreads();

    // combine 4 waves' partials, write chunk-partial to workspace
    float* numC = numP + (size_t)c * N * FOUT;
    float* denC = denP + (size_t)c * N;
#pragma unroll
    for (int k = 0; k < 4; ++k) {
        int idx = k * 256 + tid;
        int i = idx >> 6, f = idx & 63;
        float num = pC[0][i][f] + pC[1][i][f] + pC[2][i][f] + pC[3][i][f];
        numC[(size_t)(ibase + i) * FOUT + f] = num;
        if (f == 0) {
            denC[ibase + i] = pD[0][i] + pD[1][i] + pD[2][i] + pD[3][i];
        }
    }
}

// Kernel 3: sum chunk partials, divide, ELU, store.
__global__ __launch_bounds__(256) void gat_combine(
    const float* __restrict__ numP, const float* __restrict__ denP,
    float* __restrict__ out) {
    int idx = blockIdx.x * 256 + threadIdx.x;
    int row = idx >> 6;
    float num = 0.f, den = 0.f;
#pragma unroll
    for (int c = 0; c < CSPLIT; ++c) {
        num += numP[(size_t)c * N * FOUT + idx];
        den += denP[(size_t)c * N + row];
    }
    float v = num / den;
    out[idx] = (v > 0.f) ? v : expm1f(v);
}

extern "C" void kernel_launch(void* const* d_in, const int* in_sizes, int n_in,
                              void* d_out, int out_size, void* d_ws, size_t ws_size,
                              hipStream_t stream) {
    const float* h = (const float*)d_in[0];
    const int* adj = (const int*)d_in[1];
    const float* W = (const float*)d_in[2];
    const float* a = (const float*)d_in[3];
    float* out = (float*)d_out;

    char* ws = (char*)d_ws;
    __hip_bfloat16* whT = (__hip_bfloat16*)ws;                       // 1 MB
    float* s_src = (float*)(ws + (size_t)FOUT * N * sizeof(__hip_bfloat16));
    float* s_dst = s_src + N;                                        // +64 KB
    float* numP = s_dst + N;                                         // 4*8192*64*4 = 8 MB
    float* denP = numP + (size_t)CSPLIT * N * FOUT;                  // 128 KB

    hipLaunchKernelGGL(wh_kernel, dim3(N / 4), dim3(256), 0, stream,
                       h, W, a, whT, s_src, s_dst);
    hipLaunchKernelGGL(gat_partial, dim3((N / 16) * CSPLIT), dim3(256), 0, stream,
                       adj, whT, s_src, s_dst, numP, denP);
    hipLaunchKernelGGL(gat_combine, dim3(N * FOUT / 256), dim3(256), 0, stream,
                       numP, denP, out);
}

// Round 3
// 119.545 us; speedup vs baseline: 1.1528x; 1.1528x over previous
//
#include <hip/hip_runtime.h>
#include <hip/hip_bf16.h>

#define N 8192
#define FIN 128
#define FOUT 64
#define CSPLIT 2
#define TILE_C 256            // adj cols per LDS tile
#define CHUNK (N / CSPLIT)    // 4096 cols per block
#define NT (CHUNK / TILE_C)   // 16 tiles (even -> last tile in buf 1)

typedef __attribute__((ext_vector_type(4))) float f32x4;
typedef __attribute__((ext_vector_type(4))) int i32x4;
typedef __attribute__((ext_vector_type(8))) short bf16x8;

#define GLOAD_LDS16(gp, lp)                                                    \
    __builtin_amdgcn_global_load_lds(                                          \
        (const __attribute__((address_space(1))) void*)(gp),                   \
        (__attribute__((address_space(3))) void*)(lp), 16, 0, 0)

__device__ __forceinline__ short f2bf(float x) {
    __hip_bfloat16 b = __float2bfloat16(x);
    union { __hip_bfloat16 b; short s; } u; u.b = b; return u.s;
}

// Kernel 1: Wh = h @ W (store transposed bf16), s_src = Wh@a1, s_dst = Wh@a2
__global__ __launch_bounds__(256) void wh_kernel(
    const float* __restrict__ h, const float* __restrict__ W,
    const float* __restrict__ a,
    __hip_bfloat16* __restrict__ whT, float* __restrict__ s_src,
    float* __restrict__ s_dst) {
    const int wave = threadIdx.x >> 6;
    const int lane = threadIdx.x & 63;   // lane = output feature f
    const int row = blockIdx.x * 4 + wave;
    const float* hr = h + (size_t)row * FIN;
    float acc = 0.f;
#pragma unroll 8
    for (int k = 0; k < FIN; ++k) {
        acc += hr[k] * W[k * FOUT + lane];
    }
    whT[(size_t)lane * N + row] = __float2bfloat16(acc);
    float s1 = acc * a[lane];
    float s2 = acc * a[FOUT + lane];
#pragma unroll
    for (int mm = 32; mm >= 1; mm >>= 1) {
        s1 += __shfl_xor(s1, mm, 64);
        s2 += __shfl_xor(s2, mm, 64);
    }
    if (lane == 0) { s_src[row] = s1; s_dst[row] = s2; }
}

// Kernel 2: partial masked-softmax attention numerators via MFMA,
// adj + s_dst tiles staged through LDS with global_load_lds (2-phase dbuf).
// Grid = (N/16)*CSPLIT blocks. Block b: rg = b>>1 (16 rows), c = b&1 (4096 cols).
// Within a tile (16 x 256), wave w computes cols [w*64, w*64+64) = 2 MFMA steps.
__global__ __launch_bounds__(256) void gat_partial(
    const int* __restrict__ adj, const __hip_bfloat16* __restrict__ whT,
    const float* __restrict__ s_src, const float* __restrict__ s_dst,
    float* __restrict__ numP, float* __restrict__ denP) {
    union SMem {
        struct { int adjb[2][16][TILE_C]; float sdl[2][TILE_C]; } s;  // 34816 B
        struct { float pC[4][16][FOUT]; float pD[4][16]; } e;         // 16640 B
    };
    __shared__ SMem sm;

    const int tid = threadIdx.x;
    const int w = tid >> 6, lane = tid & 63;
    const int m = lane & 15, kg = lane >> 4;
    const int rg = blockIdx.x >> 1;
    const int c = blockIdx.x & 1;
    const int ibase = rg * 16;
    const int colbase0 = c * CHUNK;
    const float ssrc = s_src[ibase + m];
    const int lane4 = lane * 4;          // 16B granule per lane

    f32x4 acc0 = {0,0,0,0}, acc1 = {0,0,0,0}, acc2 = {0,0,0,0}, acc3 = {0,0,0,0};
    float dsum = 0.f;

    // ---- staging: wave w loads adj rows 4w..4w+3 (1KB each); wave 0 adds s_dst ----
    auto stage = [&](int t, int buf) {
        const int gcol = colbase0 + t * TILE_C;
#pragma unroll
        for (int q = 0; q < 4; ++q) {
            const int r = 4 * w + q;
            GLOAD_LDS16(adj + (size_t)(ibase + r) * N + gcol + lane4,
                        &sm.s.adjb[buf][r][0]);
        }
        if (w == 0) {
            GLOAD_LDS16(s_dst + gcol + lane4, &sm.s.sdl[buf][0]);
        }
    };

    stage(0, 0);
    __syncthreads();   // drains vmcnt -> tile 0 ready

    for (int t = 0; t < NT; ++t) {
        const int buf = t & 1;
        if (t + 1 < NT) stage(t + 1, buf ^ 1);

#pragma unroll
        for (int st = 0; st < 2; ++st) {
            const int tc = w * 64 + st * 32 + kg * 8;
            i32x4 a0 = *(const i32x4*)&sm.s.adjb[buf][m][tc];
            i32x4 a1 = *(const i32x4*)&sm.s.adjb[buf][m][tc + 4];
            f32x4 d0 = *(const f32x4*)&sm.s.sdl[buf][tc];
            f32x4 d1 = *(const f32x4*)&sm.s.sdl[buf][tc + 4];
            const size_t gc = (size_t)colbase0 + t * TILE_C + tc;
            bf16x8 b0 = *(const bf16x8*)(whT + (size_t)(0 * 16 + m) * N + gc);
            bf16x8 b1 = *(const bf16x8*)(whT + (size_t)(1 * 16 + m) * N + gc);
            bf16x8 b2 = *(const bf16x8*)(whT + (size_t)(2 * 16 + m) * N + gc);
            bf16x8 b3 = *(const bf16x8*)(whT + (size_t)(3 * 16 + m) * N + gc);

            bf16x8 afr;
#pragma unroll
            for (int e = 0; e < 4; ++e) {
                float x = ssrc + d0[e];
                x = (x >= 0.f) ? x : 0.2f * x;
                float p = (a0[e] > 0) ? __expf(x) : 0.f;
                dsum += p;
                afr[e] = f2bf(p);
            }
#pragma unroll
            for (int e = 0; e < 4; ++e) {
                float x = ssrc + d1[e];
                x = (x >= 0.f) ? x : 0.2f * x;
                float p = (a1[e] > 0) ? __expf(x) : 0.f;
                dsum += p;
                afr[4 + e] = f2bf(p);
            }

            acc0 = __builtin_amdgcn_mfma_f32_16x16x32_bf16(afr, b0, acc0, 0, 0, 0);
            acc1 = __builtin_amdgcn_mfma_f32_16x16x32_bf16(afr, b1, acc1, 0, 0, 0);
            acc2 = __builtin_amdgcn_mfma_f32_16x16x32_bf16(afr, b2, acc2, 0, 0, 0);
            acc3 = __builtin_amdgcn_mfma_f32_16x16x32_bf16(afr, b3, acc3, 0, 0, 0);
        }
        __syncthreads();  // drains vmcnt (stage t+1 done) + everyone done with buf
    }

    // denominator: lanes l, l^16, l^32, l^48 share row m
    dsum += __shfl_xor(dsum, 16, 64);
    dsum += __shfl_xor(dsum, 32, 64);

    // epilogue: smem reuse is safe (last compute used buf 1; loop ended with barrier)
#pragma unroll
    for (int r = 0; r < 4; ++r) {
        sm.e.pC[w][kg * 4 + r][0 * 16 + m] = acc0[r];
        sm.e.pC[w][kg * 4 + r][1 * 16 + m] = acc1[r];
        sm.e.pC[w][kg * 4 + r][2 * 16 + m] = acc2[r];
        sm.e.pC[w][kg * 4 + r][3 * 16 + m] = acc3[r];
    }
    if (kg == 0) sm.e.pD[w][m] = dsum;
    __syncthreads();

    float* numC = numP + (size_t)c * N * FOUT;
    float* denC = denP + (size_t)c * N;
#pragma unroll
    for (int k = 0; k < 4; ++k) {
        int idx = k * 256 + tid;
        int i = idx >> 6, f = idx & 63;
        float num = sm.e.pC[0][i][f] + sm.e.pC[1][i][f] + sm.e.pC[2][i][f] + sm.e.pC[3][i][f];
        numC[(size_t)(ibase + i) * FOUT + f] = num;
        if (f == 0) {
            denC[ibase + i] = sm.e.pD[0][i] + sm.e.pD[1][i] + sm.e.pD[2][i] + sm.e.pD[3][i];
        }
    }
}

// Kernel 3: sum chunk partials, divide, ELU, store.
__global__ __launch_bounds__(256) void gat_combine(
    const float* __restrict__ numP, const float* __restrict__ denP,
    float* __restrict__ out) {
    int idx = blockIdx.x * 256 + threadIdx.x;
    int row = idx >> 6;
    float num = 0.f, den = 0.f;
#pragma unroll
    for (int cc = 0; cc < CSPLIT; ++cc) {
        num += numP[(size_t)cc * N * FOUT + idx];
        den += denP[(size_t)cc * N + row];
    }
    float v = num / den;
    out[idx] = (v > 0.f) ? v : expm1f(v);
}

extern "C" void kernel_launch(void* const* d_in, const int* in_sizes, int n_in,
                              void* d_out, int out_size, void* d_ws, size_t ws_size,
                              hipStream_t stream) {
    const float* h = (const float*)d_in[0];
    const int* adj = (const int*)d_in[1];
    const float* W = (const float*)d_in[2];
    const float* a = (const float*)d_in[3];
    float* out = (float*)d_out;

    char* ws = (char*)d_ws;
    __hip_bfloat16* whT = (__hip_bfloat16*)ws;                       // 1 MB
    float* s_src = (float*)(ws + (size_t)FOUT * N * sizeof(__hip_bfloat16));
    float* s_dst = s_src + N;                                        // +64 KB
    float* numP = s_dst + N;                                         // 2*8192*64*4 = 4 MB
    float* denP = numP + (size_t)CSPLIT * N * FOUT;                  // 64 KB

    hipLaunchKernelGGL(wh_kernel, dim3(N / 4), dim3(256), 0, stream,
                       h, W, a, whT, s_src, s_dst);
    hipLaunchKernelGGL(gat_partial, dim3((N / 16) * CSPLIT), dim3(256), 0, stream,
                       adj, whT, s_src, s_dst, numP, denP);
    hipLaunchKernelGGL(gat_combine, dim3(N * FOUT / 256), dim3(256), 0, stream,
                       numP, denP, out);
}